// Round 1
// baseline (301.961 us; speedup 1.0000x reference)
//
#include <hip/hip_runtime.h>
#include <math.h>

#define EMB_DIM 64
#define MAXL    64      // bag length cap (problem uses 50)
#define NWAVE   4

__global__ __launch_bounds__(256, 4)
void pooled_attn_kernel(const int* __restrict__ input_,
                        const int* __restrict__ offsets,
                        const float* __restrict__ emb,
                        const float* __restrict__ proj_w,
                        const float* __restrict__ proj_b,
                        const float* __restrict__ att_h,
                        float* __restrict__ out,
                        int n_bags, int n_total)
{
    __shared__ float e_lds[MAXL][EMB_DIM];   // gathered embedding rows
    __shared__ float att_lds[MAXL];          // per-index logits
    __shared__ int   idx_lds[MAXL];
    __shared__ float partial[NWAVE][EMB_DIM];

    const int b    = blockIdx.x;
    const int tid  = threadIdx.x;
    const int lane = tid & 63;
    const int w    = tid >> 6;

    const int s     = offsets[b];
    const int e_end = (b + 1 < n_bags) ? offsets[b + 1] : n_total;
    int L = e_end - s;
    if (L > MAXL) L = MAXL;
    if (L < 0) L = 0;

    // lane a holds proj_w row a (W[a, 0..63]) in 64 VGPRs
    float4 w4[16];
    {
        const float4* wrow = (const float4*)(proj_w + lane * EMB_DIM);
        #pragma unroll
        for (int j = 0; j < 16; ++j) w4[j] = wrow[j];
    }
    const float bias = proj_b[lane];
    const float hval = att_h[lane];

    // stage bag indices
    if (tid < L) idx_lds[tid] = input_[s + tid];
    __syncthreads();

    // gather rows into LDS: 16 lanes per row (float4 each), 4 rows per wave-iter
    {
        const int sub = lane & 15;   // float4 slot within row
        const int rl  = lane >> 4;   // row within group of 4
        for (int r0 = w * 4; r0 < L; r0 += NWAVE * 4) {
            int r = r0 + rl;
            if (r < L) {
                int idx = idx_lds[r];
                const float4* src = (const float4*)(emb + (size_t)idx * EMB_DIM);
                ((float4*)e_lds[r])[sub] = src[sub];
            }
        }
    }
    __syncthreads();

    // attention logits: wave w handles indices i = w, w+4, ...
    for (int i = w; i < L; i += NWAVE) {
        float z = bias;
        const float4* ev = (const float4*)e_lds[i];
        #pragma unroll
        for (int j = 0; j < 16; ++j) {
            float4 e4 = ev[j];                 // LDS broadcast (free)
            z = fmaf(w4[j].x, e4.x, z);
            z = fmaf(w4[j].y, e4.y, z);
            z = fmaf(w4[j].z, e4.z, z);
            z = fmaf(w4[j].w, e4.w, z);
        }
        // tanh(z) = 1 - 2/(exp(2z)+1)  (stable for all z)
        float ex = __expf(2.0f * z);
        float t  = 1.0f - 2.0f / (ex + 1.0f);
        float v  = t * hval;
        #pragma unroll
        for (int o = 32; o; o >>= 1) v += __shfl_xor(v, o, 64);
        if (lane == 0) att_lds[i] = v;
    }
    __syncthreads();

    // softmax stats (redundant per thread; broadcast LDS reads, cheap)
    float m = -INFINITY;
    for (int i = 0; i < L; ++i) m = fmaxf(m, att_lds[i]);
    float total = 0.0f;
    for (int i = 0; i < L; ++i) total += __expf(att_lds[i] - m);
    const float inv_total = 1.0f / total;

    // weighted pooling: lane = output dim, waves split indices
    float acc = 0.0f;
    for (int i = w; i < L; i += NWAVE) {
        float wt = __expf(att_lds[i] - m) * inv_total;
        acc = fmaf(wt, e_lds[i][lane], acc);
    }
    partial[w][lane] = acc;
    __syncthreads();

    if (tid < EMB_DIM) {
        float r = partial[0][tid] + partial[1][tid] + partial[2][tid] + partial[3][tid];
        out[(size_t)b * EMB_DIM + tid] = r;
    }
}

extern "C" void kernel_launch(void* const* d_in, const int* in_sizes, int n_in,
                              void* d_out, int out_size, void* d_ws, size_t ws_size,
                              hipStream_t stream) {
    const int*   input_  = (const int*)d_in[0];
    const int*   offsets = (const int*)d_in[1];
    const float* emb     = (const float*)d_in[2];
    const float* proj_w  = (const float*)d_in[3];
    const float* proj_b  = (const float*)d_in[4];
    const float* att_h   = (const float*)d_in[5];
    float* out = (float*)d_out;

    const int N = in_sizes[0];
    const int B = in_sizes[1];

    pooled_attn_kernel<<<B, 256, 0, stream>>>(input_, offsets, emb, proj_w,
                                              proj_b, att_h, out, B, N);
}

// Round 2
// 103.997 us; speedup vs baseline: 2.9036x; 2.9036x over previous
//
#include <hip/hip_runtime.h>
#include <hip/hip_bf16.h>
#include <math.h>

#define EMB_DIM 64
#define MAXL    64      // bag length cap (problem uses 50)
#define LDS_K   72      // padded bf16 row stride (144 B) -> 2-way bank alias (free)

typedef __attribute__((ext_vector_type(8))) short bf16x8;
typedef __attribute__((ext_vector_type(4))) float f32x4;

static __device__ __forceinline__ ushort f2bf(float x) {
    __hip_bfloat16 h = __float2bfloat16(x);   // RNE
    return __builtin_bit_cast(ushort, h);
}

__global__ void convert_w_kernel(const float* __restrict__ proj_w,
                                 ushort* __restrict__ w_bf) {
    int t = blockIdx.x * 256 + threadIdx.x;
    if (t < EMB_DIM * EMB_DIM) w_bf[t] = f2bf(proj_w[t]);
}

__global__ __launch_bounds__(256, 4)
void pooled_attn_mfma(const int* __restrict__ input_,
                      const int* __restrict__ offsets,
                      const float* __restrict__ emb,
                      const ushort* __restrict__ w_bf,   // [64][64] bf16 row-major
                      const float* __restrict__ proj_b,
                      const float* __restrict__ att_h,
                      float* __restrict__ out,
                      int n_bags, int n_total)
{
    __shared__ ushort E[MAXL][LDS_K];        // gathered rows, bf16, zero-padded
    __shared__ float  att_lds[MAXL];
    __shared__ int    idx_lds[MAXL];
    __shared__ float  partial[4][EMB_DIM];

    const int b    = blockIdx.x;
    const int tid  = threadIdx.x;
    const int lane = tid & 63;
    const int w    = tid >> 6;

    const int s0    = offsets[b];
    const int e_end = (b + 1 < n_bags) ? offsets[b + 1] : n_total;
    int L = e_end - s0;
    if (L > MAXL) L = MAXL;
    if (L < 0) L = 0;

    if (tid < L) idx_lds[tid] = input_[s0 + tid];
    __syncthreads();

    // Gather: 4 iters x 16 rows; thread -> (row r, 16B fp32 chunk c).
    // Global: 16 lanes x float4 = 256 B contiguous per row (coalesced).
    {
        const int c  = tid & 15;
        const int r0 = tid >> 4;
        #pragma unroll
        for (int it = 0; it < 4; ++it) {
            int r = it * 16 + r0;
            ushort4 pk = make_ushort4(0, 0, 0, 0);
            if (r < L) {
                const float4 v = ((const float4*)(emb + (size_t)idx_lds[r] * EMB_DIM))[c];
                pk = make_ushort4(f2bf(v.x), f2bf(v.y), f2bf(v.z), f2bf(v.w));
            }
            *(ushort4*)&E[r][c * 4] = pk;   // rows >= L stay zero
        }
    }
    __syncthreads();

    // Projection: Z[i][a] = sum_k E[i][k] * W[a][k], via 16x16x32 bf16 MFMA.
    // Wave w owns rows 16w..16w+15; 4 N-tiles (a) x 2 K-steps = 8 MFMAs.
    f32x4 acc[4];
    #pragma unroll
    for (int t = 0; t < 4; ++t) acc[t] = (f32x4){0.f, 0.f, 0.f, 0.f};

    const int arow = w * 16 + (lane & 15);
    const int kg   = (lane >> 4) * 8;
    #pragma unroll
    for (int s = 0; s < 2; ++s) {
        bf16x8 a = *(const bf16x8*)&E[arow][s * 32 + kg];
        #pragma unroll
        for (int t = 0; t < 4; ++t) {
            // B-frag: col a = (lane&15)+16t of B = row a of W (contiguous in k).
            bf16x8 bb = *(const bf16x8*)&w_bf[((lane & 15) + 16 * t) * EMB_DIM + s * 32 + kg];
            acc[t] = __builtin_amdgcn_mfma_f32_16x16x32_bf16(a, bb, acc[t], 0, 0, 0);
        }
    }

    // Epilogue: att_i = sum_a tanh(z_ia + b_a) * h_a.
    // Lane holds z for col a=(lane&15)+16t, rows (lane>>4)*4+reg (+16w).
    {
        const int acol = lane & 15;
        float vatt[4] = {0.f, 0.f, 0.f, 0.f};
        #pragma unroll
        for (int t = 0; t < 4; ++t) {
            float bb = proj_b[acol + 16 * t];
            float hh = att_h[acol + 16 * t];
            #pragma unroll
            for (int r = 0; r < 4; ++r) {
                float z  = acc[t][r] + bb;
                float ex = __expf(2.0f * z);
                float th = 1.0f - 2.0f / (ex + 1.0f);   // tanh, stable
                vatt[r]  = fmaf(th, hh, vatt[r]);
            }
        }
        #pragma unroll
        for (int r = 0; r < 4; ++r) {
            float v = vatt[r];
            v += __shfl_xor(v, 1, 16);
            v += __shfl_xor(v, 2, 16);
            v += __shfl_xor(v, 4, 16);
            v += __shfl_xor(v, 8, 16);
            vatt[r] = v;
        }
        if ((lane & 15) == 0) {
            #pragma unroll
            for (int r = 0; r < 4; ++r)
                att_lds[w * 16 + (lane >> 4) * 4 + r] = vatt[r];
        }
    }
    __syncthreads();

    // Wave-parallel softmax stats (each wave redundantly; all read-only here).
    float av = (lane < L) ? att_lds[lane] : -INFINITY;
    float m = av;
    #pragma unroll
    for (int o = 32; o; o >>= 1) m = fmaxf(m, __shfl_xor(m, o, 64));
    float ee = (lane < L) ? __expf(av - m) : 0.0f;
    float ss = ee;
    #pragma unroll
    for (int o = 32; o; o >>= 1) ss += __shfl_xor(ss, o, 64);
    const float inv = 1.0f / ss;
    __syncthreads();                     // everyone done reading att_lds
    if (w == 0 && lane < L) att_lds[lane] = ee * inv;   // final weights
    __syncthreads();

    // Pooling: lane = output dim, waves split indices. E read bf16 -> fp32.
    float acc_p = 0.0f;
    for (int i = w; i < L; i += 4) {
        float wt = att_lds[i];                                   // broadcast
        float ev = __uint_as_float(((unsigned)E[i][lane]) << 16); // bf16 -> f32
        acc_p = fmaf(wt, ev, acc_p);
    }
    partial[w][lane] = acc_p;
    __syncthreads();

    if (tid < EMB_DIM) {
        out[(size_t)b * EMB_DIM + tid] =
            partial[0][tid] + partial[1][tid] + partial[2][tid] + partial[3][tid];
    }
}

extern "C" void kernel_launch(void* const* d_in, const int* in_sizes, int n_in,
                              void* d_out, int out_size, void* d_ws, size_t ws_size,
                              hipStream_t stream) {
    const int*   input_  = (const int*)d_in[0];
    const int*   offsets = (const int*)d_in[1];
    const float* emb     = (const float*)d_in[2];
    const float* proj_w  = (const float*)d_in[3];
    const float* proj_b  = (const float*)d_in[4];
    const float* att_h   = (const float*)d_in[5];
    float* out = (float*)d_out;

    const int N = in_sizes[0];
    const int B = in_sizes[1];

    ushort* w_bf = (ushort*)d_ws;   // 64*64*2 = 8 KB

    convert_w_kernel<<<(EMB_DIM * EMB_DIM + 255) / 256, 256, 0, stream>>>(proj_w, w_bf);
    pooled_attn_mfma<<<B, 256, 0, stream>>>(input_, offsets, emb, w_bf,
                                            proj_b, att_h, out, B, N);
}

// Round 3
// 79.384 us; speedup vs baseline: 3.8038x; 1.3101x over previous
//
#include <hip/hip_runtime.h>
#include <hip/hip_bf16.h>
#include <math.h>

#define EMB_DIM 64
#define MAXL    64      // bag length cap (problem uses 50)
#define LDS_K   72      // padded bf16 row stride (144 B): frag reads 2-way alias (free)
#define BPB     4       // bags (waves) per block

typedef __attribute__((ext_vector_type(8))) short bf16x8;
typedef __attribute__((ext_vector_type(4))) float f32x4;

static __device__ __forceinline__ ushort f2bf(float x) {
    __hip_bfloat16 h = __float2bfloat16(x);   // RNE
    return __builtin_bit_cast(ushort, h);
}
static __device__ __forceinline__ float bf2f(ushort u) {
    return __uint_as_float(((unsigned)u) << 16);
}

__global__ void convert_w_kernel(const float* __restrict__ proj_w,
                                 ushort* __restrict__ w_bf) {
    int t = blockIdx.x * 256 + threadIdx.x;
    if (t < EMB_DIM * EMB_DIM) w_bf[t] = f2bf(proj_w[t]);
}

// One wave per bag; no __syncthreads anywhere (each wave owns its LDS slice).
__global__ __launch_bounds__(256, 4)
void pooled_attn_wavebag(const int* __restrict__ input_,
                         const int* __restrict__ offsets,
                         const float* __restrict__ emb,
                         const ushort* __restrict__ w_bf,   // [64][64] bf16
                         const float* __restrict__ proj_b,
                         const float* __restrict__ att_h,
                         float* __restrict__ out,
                         int n_bags, int n_total)
{
    __shared__ ushort E_all[BPB][MAXL][LDS_K];
    __shared__ float  A_all[BPB][MAXL];

    const int tid  = threadIdx.x;
    const int lane = tid & 63;
    const int w    = tid >> 6;
    const int b    = blockIdx.x * BPB + w;
    if (b >= n_bags) return;          // wave-uniform exit; no barriers in kernel

    ushort (*E)[LDS_K] = E_all[w];
    float* att = A_all[w];

    const int s0    = offsets[b];
    const int e_end = (b + 1 < n_bags) ? offsets[b + 1] : n_total;
    int L = e_end - s0;
    if (L > MAXL) L = MAXL;
    if (L < 0) L = 0;

    // lane i holds index i of the bag
    int myidx = 0;
    if (lane < L) myidx = input_[s0 + lane];

    const int c  = lane & 15;   // float4 chunk within a 256-B row
    const int rg = lane >> 4;   // row subgroup (4 rows per load instr)

    // ---- gather: 64 rows, 2 batches of 8 in-flight float4 loads per lane ----
    #pragma unroll
    for (int half = 0; half < 2; ++half) {
        float4 v[8];
        #pragma unroll
        for (int it = 0; it < 8; ++it) {
            const int r   = (half * 8 + it) * 4 + rg;
            const int idx = __shfl(myidx, r, 64);
            v[it] = make_float4(0.f, 0.f, 0.f, 0.f);
            if (r < L)
                v[it] = ((const float4*)(emb + (size_t)idx * EMB_DIM))[c];
        }
        #pragma unroll
        for (int it = 0; it < 8; ++it) {
            const int r = (half * 8 + it) * 4 + rg;
            *(ushort4*)&E[r][c * 4] =
                make_ushort4(f2bf(v[it].x), f2bf(v[it].y), f2bf(v[it].z), f2bf(v[it].w));
        }
    }

    // ---- hoist W B-fragments (8 x bf16x8 = 32 VGPR) and epilogue constants ----
    bf16x8 bfrag[2][4];
    #pragma unroll
    for (int s = 0; s < 2; ++s)
        #pragma unroll
        for (int t = 0; t < 4; ++t)
            bfrag[s][t] = *(const bf16x8*)&w_bf[(c + 16 * t) * EMB_DIM + s * 32 + rg * 8];
    float bbias[4], hval[4];
    #pragma unroll
    for (int t = 0; t < 4; ++t) {
        bbias[t] = proj_b[c + 16 * t];
        hval[t]  = att_h[c + 16 * t];
    }

    // ---- projection + logit epilogue, 4 chunks of 16 rows ----
    #pragma unroll
    for (int ch = 0; ch < 4; ++ch) {
        f32x4 acc[4];
        #pragma unroll
        for (int t = 0; t < 4; ++t) acc[t] = (f32x4){0.f, 0.f, 0.f, 0.f};
        #pragma unroll
        for (int s = 0; s < 2; ++s) {
            bf16x8 a = *(const bf16x8*)&E[ch * 16 + c][s * 32 + rg * 8];
            #pragma unroll
            for (int t = 0; t < 4; ++t)
                acc[t] = __builtin_amdgcn_mfma_f32_16x16x32_bf16(a, bfrag[s][t], acc[t], 0, 0, 0);
        }
        // C layout: col = lane&15 (=c), row = rg*4 + reg
        float vatt[4] = {0.f, 0.f, 0.f, 0.f};
        #pragma unroll
        for (int t = 0; t < 4; ++t) {
            #pragma unroll
            for (int r = 0; r < 4; ++r) {
                float z  = acc[t][r] + bbias[t];
                float ex = __expf(2.0f * z);
                float th = 1.0f - 2.0f / (ex + 1.0f);   // tanh, stable
                vatt[r]  = fmaf(th, hval[t], vatt[r]);
            }
        }
        #pragma unroll
        for (int r = 0; r < 4; ++r) {
            float v = vatt[r];
            v += __shfl_xor(v, 1, 16);
            v += __shfl_xor(v, 2, 16);
            v += __shfl_xor(v, 4, 16);
            v += __shfl_xor(v, 8, 16);
            vatt[r] = v;
        }
        if (c == 0) {
            #pragma unroll
            for (int r = 0; r < 4; ++r)
                att[ch * 16 + rg * 4 + r] = vatt[r];
        }
    }

    // ---- wave-parallel softmax; lane i keeps weight for index i ----
    float av = (lane < L) ? att[lane] : -INFINITY;
    float m = av;
    #pragma unroll
    for (int o = 32; o; o >>= 1) m = fmaxf(m, __shfl_xor(m, o, 64));
    float ee = (lane < L) ? __expf(av - m) : 0.0f;
    float ss = ee;
    #pragma unroll
    for (int o = 32; o; o >>= 1) ss += __shfl_xor(ss, o, 64);
    const float wt = ee * (1.0f / ss);      // 0 for lanes >= L

    // ---- pooling: lane = output dim; 4 accumulators break the FMA chain ----
    float p0 = 0.f, p1 = 0.f, p2 = 0.f, p3 = 0.f;
    const unsigned wtb = __float_as_uint(wt);
    #pragma unroll
    for (int i = 0; i < MAXL; i += 4) {
        float w0 = __uint_as_float(__builtin_amdgcn_readlane(wtb, i + 0));
        float w1 = __uint_as_float(__builtin_amdgcn_readlane(wtb, i + 1));
        float w2 = __uint_as_float(__builtin_amdgcn_readlane(wtb, i + 2));
        float w3 = __uint_as_float(__builtin_amdgcn_readlane(wtb, i + 3));
        p0 = fmaf(w0, bf2f(E[i + 0][lane]), p0);
        p1 = fmaf(w1, bf2f(E[i + 1][lane]), p1);
        p2 = fmaf(w2, bf2f(E[i + 2][lane]), p2);
        p3 = fmaf(w3, bf2f(E[i + 3][lane]), p3);
    }
    out[(size_t)b * EMB_DIM + lane] = (p0 + p1) + (p2 + p3);
}

extern "C" void kernel_launch(void* const* d_in, const int* in_sizes, int n_in,
                              void* d_out, int out_size, void* d_ws, size_t ws_size,
                              hipStream_t stream) {
    const int*   input_  = (const int*)d_in[0];
    const int*   offsets = (const int*)d_in[1];
    const float* emb     = (const float*)d_in[2];
    const float* proj_w  = (const float*)d_in[3];
    const float* proj_b  = (const float*)d_in[4];
    const float* att_h   = (const float*)d_in[5];
    float* out = (float*)d_out;

    const int N = in_sizes[0];
    const int B = in_sizes[1];

    ushort* w_bf = (ushort*)d_ws;   // 64*64*2 = 8 KB

    convert_w_kernel<<<(EMB_DIM * EMB_DIM + 255) / 256, 256, 0, stream>>>(proj_w, w_bf);
    pooled_attn_wavebag<<<(B + BPB - 1) / BPB, 256, 0, stream>>>(
        input_, offsets, emb, w_bf, proj_b, att_h, out, B, N);
}

// Round 4
// 74.314 us; speedup vs baseline: 4.0633x; 1.0682x over previous
//
#include <hip/hip_runtime.h>
#include <hip/hip_bf16.h>
#include <math.h>

#define EMB_DIM 64
#define MAXL    64      // bag length cap (problem uses 50)
#define BPB     4       // bags (waves) per block

typedef __attribute__((ext_vector_type(8))) short bf16x8;
typedef __attribute__((ext_vector_type(4))) float f32x4;

static __device__ __forceinline__ ushort f2bf(float x) {
    __hip_bfloat16 h = __float2bfloat16(x);   // RNE
    return __builtin_bit_cast(ushort, h);
}
static __device__ __forceinline__ float bf2f(ushort u) {
    return __uint_as_float(((unsigned)u) << 16);
}
static __device__ __forceinline__ bf16x8 pack8(float4 a, float4 b) {
    bf16x8 r;
    r[0] = (short)f2bf(a.x); r[1] = (short)f2bf(a.y);
    r[2] = (short)f2bf(a.z); r[3] = (short)f2bf(a.w);
    r[4] = (short)f2bf(b.x); r[5] = (short)f2bf(b.y);
    r[6] = (short)f2bf(b.z); r[7] = (short)f2bf(b.w);
    return r;
}

__global__ void convert_w_kernel(const float* __restrict__ proj_w,
                                 ushort* __restrict__ w_bf) {
    int t = blockIdx.x * 256 + threadIdx.x;
    if (t < EMB_DIM * EMB_DIM) w_bf[t] = f2bf(proj_w[t]);
}

// One wave per bag. E lives entirely in registers in MFMA A-fragment layout:
// lane l owns rows 16*ch + (l&15), dims [s*32 + (l>>4)*8, +8).  Only LDS is
// the 64-float logit buffer per bag (256 B).  No __syncthreads anywhere.
__global__ __launch_bounds__(256)
void pooled_attn_reg(const int* __restrict__ input_,
                     const int* __restrict__ offsets,
                     const float* __restrict__ emb,
                     const ushort* __restrict__ w_bf,   // [64][64] bf16
                     const float* __restrict__ proj_b,
                     const float* __restrict__ att_h,
                     float* __restrict__ out,
                     int n_bags, int n_total)
{
    __shared__ float A_all[BPB][MAXL];

    const int tid  = threadIdx.x;
    const int lane = tid & 63;
    const int w    = tid >> 6;
    const int b    = blockIdx.x * BPB + w;
    if (b >= n_bags) return;          // wave-uniform; no barriers in kernel

    float* att = A_all[w];

    const int s0    = offsets[b];
    const int e_end = (b + 1 < n_bags) ? offsets[b + 1] : n_total;
    int L = e_end - s0;
    if (L > MAXL) L = MAXL;
    if (L < 0) L = 0;

    int myidx = (lane < L) ? input_[s0 + lane] : 0;

    const int c  = lane & 15;   // A-frag row-within-chunk / B-frag col
    const int rg = lane >> 4;   // k-subgroup

    // ---- hoist W B-fragments (32 VGPR) + epilogue constants ----
    bf16x8 bfrag[2][4];
    #pragma unroll
    for (int s = 0; s < 2; ++s)
        #pragma unroll
        for (int t = 0; t < 4; ++t)
            bfrag[s][t] = *(const bf16x8*)&w_bf[(c + 16 * t) * EMB_DIM + s * 32 + rg * 8];
    float bbias[4], hval[4];
    #pragma unroll
    for (int t = 0; t < 4; ++t) {
        bbias[t] = proj_b[c + 16 * t];
        hval[t]  = att_h[c + 16 * t];
    }

    // ---- gather directly into A-fragment registers (2 halves of 8 loads) ----
    bf16x8 ea[4][2];   // [chunk][k-step], 32 VGPR persistent
    #pragma unroll
    for (int hf = 0; hf < 2; ++hf) {
        float4 st[8];
        #pragma unroll
        for (int i = 0; i < 8; ++i) st[i] = make_float4(0.f, 0.f, 0.f, 0.f);
        #pragma unroll
        for (int chh = 0; chh < 2; ++chh) {
            const int ch  = hf * 2 + chh;
            const int row = 16 * ch + c;
            const int idx = __shfl(myidx, row, 64);
            const float4* rp = (const float4*)(emb + (size_t)idx * EMB_DIM);
            if (row < L) {
                st[chh * 4 + 0] = rp[rg * 2 + 0];       // dims rg*8   .. +4
                st[chh * 4 + 1] = rp[rg * 2 + 1];       // dims rg*8+4 .. +4
                st[chh * 4 + 2] = rp[8 + rg * 2 + 0];   // dims 32+rg*8
                st[chh * 4 + 3] = rp[8 + rg * 2 + 1];
            }
        }
        #pragma unroll
        for (int chh = 0; chh < 2; ++chh) {
            const int ch = hf * 2 + chh;
            ea[ch][0] = pack8(st[chh * 4 + 0], st[chh * 4 + 1]);
            ea[ch][1] = pack8(st[chh * 4 + 2], st[chh * 4 + 3]);
        }
    }

    // ---- projection + logit epilogue, 4 chunks of 16 rows ----
    #pragma unroll
    for (int ch = 0; ch < 4; ++ch) {
        f32x4 acc[4];
        #pragma unroll
        for (int t = 0; t < 4; ++t) acc[t] = (f32x4){0.f, 0.f, 0.f, 0.f};
        #pragma unroll
        for (int t = 0; t < 4; ++t)
            acc[t] = __builtin_amdgcn_mfma_f32_16x16x32_bf16(ea[ch][0], bfrag[0][t], acc[t], 0, 0, 0);
        #pragma unroll
        for (int t = 0; t < 4; ++t)
            acc[t] = __builtin_amdgcn_mfma_f32_16x16x32_bf16(ea[ch][1], bfrag[1][t], acc[t], 0, 0, 0);

        // C layout: col = c (att dim a = c+16t), row-in-chunk = rg*4 + r
        float vatt[4] = {0.f, 0.f, 0.f, 0.f};
        #pragma unroll
        for (int t = 0; t < 4; ++t) {
            #pragma unroll
            for (int r = 0; r < 4; ++r) {
                float z  = acc[t][r] + bbias[t];
                float ex = __expf(2.0f * z);
                float th = 1.0f - 2.0f / (ex + 1.0f);   // tanh, stable
                vatt[r]  = fmaf(th, hval[t], vatt[r]);
            }
        }
        #pragma unroll
        for (int r = 0; r < 4; ++r) {
            float v = vatt[r];
            v += __shfl_xor(v, 1, 16);
            v += __shfl_xor(v, 2, 16);
            v += __shfl_xor(v, 4, 16);
            v += __shfl_xor(v, 8, 16);
            vatt[r] = v;
        }
        if (c == 0) {
            f32x4 v4 = {vatt[0], vatt[1], vatt[2], vatt[3]};
            *(f32x4*)&att[16 * ch + 4 * rg] = v4;       // ds_write_b128
        }
    }

    // ---- wave-parallel softmax stats (same-wave LDS, no barrier needed) ----
    float av = (lane < L) ? att[lane] : -INFINITY;
    float m = av;
    #pragma unroll
    for (int o = 32; o; o >>= 1) m = fmaxf(m, __shfl_xor(m, o, 64));
    float ee = (lane < L) ? __expf(av - m) : 0.0f;
    float ss = ee;
    #pragma unroll
    for (int o = 32; o; o >>= 1) ss += __shfl_xor(ss, o, 64);
    const float inv = 1.0f / ss;

    // ---- pooling from registers: lane owns rows {c+16ch}, dims {s*32+rg*8..+8} ----
    float pool[16];
    #pragma unroll
    for (int k = 0; k < 16; ++k) pool[k] = 0.f;
    #pragma unroll
    for (int ch = 0; ch < 4; ++ch) {
        const int row = 16 * ch + c;
        float wt = (row < L) ? __expf(att[row] - m) * inv : 0.f;
        #pragma unroll
        for (int s = 0; s < 2; ++s)
            #pragma unroll
            for (int j = 0; j < 8; ++j)
                pool[s * 8 + j] = fmaf(wt, bf2f((ushort)ea[ch][s][j]), pool[s * 8 + j]);
    }
    // reduce across the 16 c-lanes (rows), leaves every lane with its 16 dims
    #pragma unroll
    for (int o = 1; o < 16; o <<= 1) {
        #pragma unroll
        for (int k = 0; k < 16; ++k) pool[k] += __shfl_xor(pool[k], o, 16);
    }
    if (c == 0) {
        float4* op = (float4*)(out + (size_t)b * EMB_DIM);
        op[rg * 2 + 0]     = make_float4(pool[0],  pool[1],  pool[2],  pool[3]);
        op[rg * 2 + 1]     = make_float4(pool[4],  pool[5],  pool[6],  pool[7]);
        op[8 + rg * 2 + 0] = make_float4(pool[8],  pool[9],  pool[10], pool[11]);
        op[8 + rg * 2 + 1] = make_float4(pool[12], pool[13], pool[14], pool[15]);
    }
}

extern "C" void kernel_launch(void* const* d_in, const int* in_sizes, int n_in,
                              void* d_out, int out_size, void* d_ws, size_t ws_size,
                              hipStream_t stream) {
    const int*   input_  = (const int*)d_in[0];
    const int*   offsets = (const int*)d_in[1];
    const float* emb     = (const float*)d_in[2];
    const float* proj_w  = (const float*)d_in[3];
    const float* proj_b  = (const float*)d_in[4];
    const float* att_h   = (const float*)d_in[5];
    float* out = (float*)d_out;

    const int N = in_sizes[0];
    const int B = in_sizes[1];

    ushort* w_bf = (ushort*)d_ws;   // 64*64*2 = 8 KB

    convert_w_kernel<<<(EMB_DIM * EMB_DIM + 255) / 256, 256, 0, stream>>>(proj_w, w_bf);
    pooled_attn_reg<<<(B + BPB - 1) / BPB, 256, 0, stream>>>(
        input_, offsets, emb, w_bf, proj_b, att_h, out, B, N);
}